// Round 1
// baseline (174.279 us; speedup 1.0000x reference)
//
#include <hip/hip_runtime.h>
#include <hip/hip_bf16.h>

// Problem constants: A=8 agents, B=64 envs, S=1024 seq, H=128 hidden.
#define AN 8
#define BN 64
#define SN 1024
#define HN 128
// rows M = A*B*S = 524288, strips of 16 rows = 32768 strips
#define NSTRIPS ((AN * BN * SN) / 16)

typedef __attribute__((ext_vector_type(8))) short bf16x8;
typedef __attribute__((ext_vector_type(4))) float f32x4;

__device__ __forceinline__ short f2bf(float f) {
    unsigned u = __builtin_bit_cast(unsigned, f);
    // round-to-nearest-even to bf16
    unsigned r = (u + 0x7fffu + ((u >> 16) & 1u)) >> 16;
    return (short)r;
}

__global__ __launch_bounds__(256) void commnet_fused(
    const float* __restrict__ obs,   // (A*B, S, H)
    const float* __restrict__ rnn,   // (S, B, A, H)
    const int*   __restrict__ alive, // (A, B, S, 1)
    const float* __restrict__ W,     // (H, H) [out, in]
    const float* __restrict__ bias,  // (H,)
    float* __restrict__ out)         // (A*B, S, H)
{
    // Pre-packed B fragments in LDS: B[k][n] = W[n][k], bf16.
    // Fragment (nt, ks): lane l holds B[32*ks + 8*(l>>4) + j][16*nt + (l&15)]
    __shared__ bf16x8 Bfrag[8][4][64];   // 32 KiB

    const int tid  = threadIdx.x;
    const int lane = tid & 63;
    const int wv   = tid >> 6;

    for (int e = tid; e < 8 * 4 * 64; e += 256) {
        int l  = e & 63;
        int ks = (e >> 6) & 3;
        int nt = e >> 8;
        int col = 16 * nt + (l & 15);      // n index (W row)
        int k0  = 32 * ks + 8 * (l >> 4);  // k index (W col)
        const float* wp = W + col * HN + k0;
        float4 w0 = *(const float4*)(wp);
        float4 w1 = *(const float4*)(wp + 4);
        bf16x8 f;
        f[0] = f2bf(w0.x); f[1] = f2bf(w0.y); f[2] = f2bf(w0.z); f[3] = f2bf(w0.w);
        f[4] = f2bf(w1.x); f[5] = f2bf(w1.y); f[6] = f2bf(w1.z); f[7] = f2bf(w1.w);
        Bfrag[nt][ks][l] = f;
    }
    __syncthreads();

    const int r  = lane & 15;  // A-row within strip / D-col within 16-tile
    const int kg = lane >> 4;  // k-group (A) / row-group (D)

    // bias per lane's output columns (col = 16*nt + r), strip-invariant
    float bcol[8];
#pragma unroll
    for (int nt = 0; nt < 8; ++nt) bcol[nt] = bias[16 * nt + r];

    for (int strip = blockIdx.x * 4 + wv; strip < NSTRIPS; strip += gridDim.x * 4) {
        const int ab = strip >> 6;            // 64 strips per (a,b)
        const int s0 = (strip & 63) << 4;
        const int a  = ab >> 6;
        const int b  = ab & 63;
        const int s_r = s0 + r;

        // alive scale for this lane's A-row: alive[a,b,s] / max(sum_a' alive, 1)
        int asum = 0, mya = 0;
#pragma unroll
        for (int a2 = 0; a2 < AN; ++a2) {
            int v = alive[(a2 * BN + b) * SN + s_r];
            asum += v;
            if (a2 == a) mya = v;
        }
        const float scale = mya ? 1.0f / (float)(asum < 1 ? 1 : asum) : 0.0f;

        f32x4 acc[8];
#pragma unroll
        for (int nt = 0; nt < 8; ++nt) acc[nt] = (f32x4){0.f, 0.f, 0.f, 0.f};

        const float* arow = rnn + (s_r * BN + b) * (AN * HN) + a * HN;
#pragma unroll
        for (int ks = 0; ks < 4; ++ks) {
            const int k0 = 32 * ks + 8 * kg;
            float4 a0 = *(const float4*)(arow + k0);
            float4 a1 = *(const float4*)(arow + k0 + 4);
            bf16x8 af;
            af[0] = f2bf(a0.x * scale); af[1] = f2bf(a0.y * scale);
            af[2] = f2bf(a0.z * scale); af[3] = f2bf(a0.w * scale);
            af[4] = f2bf(a1.x * scale); af[5] = f2bf(a1.y * scale);
            af[6] = f2bf(a1.z * scale); af[7] = f2bf(a1.w * scale);
#pragma unroll
            for (int nt = 0; nt < 8; ++nt)
                acc[nt] = __builtin_amdgcn_mfma_f32_16x16x32_bf16(
                    af, Bfrag[nt][ks][lane], acc[nt], 0, 0, 0);
        }

        // Epilogue: D[row][col], row = 4*kg + rg, col = 16*nt + r.
        const int outbase = ab * (SN * HN) + s0 * HN;
#pragma unroll
        for (int nt = 0; nt < 8; ++nt) {
            const int col = 16 * nt + r;
#pragma unroll
            for (int rg = 0; rg < 4; ++rg) {
                const int orow = 4 * kg + rg;
                const int idx = outbase + orow * HN + col;
                out[idx] = acc[nt][rg] + bcol[nt] + obs[idx];
            }
        }
    }
}

extern "C" void kernel_launch(void* const* d_in, const int* in_sizes, int n_in,
                              void* d_out, int out_size, void* d_ws, size_t ws_size,
                              hipStream_t stream) {
    const float* obs   = (const float*)d_in[0];
    const float* rnn   = (const float*)d_in[1];
    const int*   alive = (const int*)d_in[2];
    const float* W     = (const float*)d_in[3];
    const float* bias  = (const float*)d_in[4];
    float* out = (float*)d_out;
    (void)in_sizes; (void)n_in; (void)d_ws; (void)ws_size; (void)out_size;

    commnet_fused<<<2048, 256, 0, stream>>>(obs, rnn, alive, W, bias, out);
}